// Round 1
// baseline (1275.617 us; speedup 1.0000x reference)
//
#include <hip/hip_runtime.h>
#include <math.h>

typedef unsigned long long u64;

#define NPROP 1000
#define KDIM 25088
#define HDIM 1024
#define NCLS 21
#define NBOX 20000      // 1000 * 20
#define NPAD 20480      // 10 runs of 2048
#define KPRE 2000
#define LOGC 4.135166556742356f

// order-preserving float->uint map (ascending)
__device__ inline unsigned ordkey(float f) {
    unsigned u = __float_as_uint(f);
    return (u & 0x80000000u) ? ~u : (u | 0x80000000u);
}
// key sorts ASCENDING == score DESCENDING, ties: lower index first (lax.top_k semantics)
__device__ inline u64 mkkey(float s, unsigned i) {
    return ((u64)(unsigned)(~ordkey(s)) << 32) | (u64)i;
}

// ---------------- ROI pool: (512,50,50) feat, 1000 proposals -> (1000, 25088) ----------------
__global__ void roi_pool_kernel(const float* __restrict__ feat, const float* __restrict__ props,
                                float* __restrict__ pooled)
{
    __shared__ int xi[14], yi[14];
    int n = blockIdx.x;
    int tid = threadIdx.x;
    if (tid < 28) {
        bool isx = tid < 14;
        int k = isx ? tid : tid - 14;
        float lo = props[n*4 + (isx ? 0 : 1)] * 0.0625f;
        float hi = props[n*4 + (isx ? 2 : 3)] * 0.0625f;
        float bsz = (hi - lo) / 7.0f;
        float g = ((float)k + 0.5f) * 0.5f;
        // replicate mul-then-add (no fma) so floor() matches reference
        float gv = __fadd_rn(lo, __fmul_rn(g, bsz));
        int v = (int)floorf(gv);
        v = v < 0 ? 0 : (v > 49 ? 49 : v);
        if (isx) xi[k] = v; else yi[k] = v;
    }
    __syncthreads();
    for (int o = tid; o < KDIM; o += 256) {
        int c = o / 49;
        int p = o - c * 49;
        int py = p / 7, px = p - py * 7;
        const float* fc = feat + (size_t)c * 2500;
        int y0 = yi[2*py] * 50, y1 = yi[2*py+1] * 50;
        int x0 = xi[2*px],      x1 = xi[2*px+1];
        float v = fmaxf(fmaxf(fc[y0+x0], fc[y0+x1]), fmaxf(fc[y1+x0], fc[y1+x1]));
        pooled[(size_t)n * KDIM + o] = v;
    }
}

// ---------------- split-K fp32 GEMM: A (Mreal x lda-rowmajor), B (K x 1024), P[s] partials ----------------
// grid (gm=8, gn=8, S); block 256. Tile 128x128, BK=8, per-lane 8x8.
__global__ __launch_bounds__(256, 4)
void gemm_splitk(const float* __restrict__ A, const float* __restrict__ B,
                 float* __restrict__ P, int Mreal, int lda, int Kseg)
{
    const int N = 1024;
    __shared__ float As[8][128];
    __shared__ float Bs[8][128];
    int bm = blockIdx.x * 128, bn = blockIdx.y * 128, s = blockIdx.z;
    int k0 = s * Kseg;
    int tid = threadIdx.x;
    int lane = tid & 63, wv = tid >> 6;
    int row = ((wv >> 1) << 6) + ((lane >> 3) << 3);   // wave 64-row half + ly*8
    int col = ((wv & 1) << 6) + ((lane & 7) << 3);
    int ar = tid >> 1, ac = (tid & 1) << 2;            // A stage: row, k-quad
    int bkr = tid >> 5, bnc = (tid & 31) << 2;         // B stage: k-row, col-quad
    float acc[8][8] = {};
    const float* Aptr = A + (size_t)(bm + ar) * lda + k0 + ac;
    bool arok = (bm + ar) < Mreal;
    const float* Bptr = B + (size_t)(k0 + bkr) * N + bn + bnc;
    int nt = Kseg >> 3;
    for (int t = 0; t < nt; ++t) {
        float4 av = make_float4(0.f, 0.f, 0.f, 0.f);
        if (arok) av = *(const float4*)(Aptr);
        float4 bv = *(const float4*)(Bptr);
        Aptr += 8; Bptr += (size_t)8 * N;
        __syncthreads();
        As[ac+0][ar] = av.x; As[ac+1][ar] = av.y; As[ac+2][ar] = av.z; As[ac+3][ar] = av.w;
        *(float4*)&Bs[bkr][bnc] = bv;
        __syncthreads();
        #pragma unroll
        for (int k = 0; k < 8; ++k) {
            float a[8], b[8];
            *(float4*)&a[0] = *(const float4*)&As[k][row];
            *(float4*)&a[4] = *(const float4*)&As[k][row+4];
            *(float4*)&b[0] = *(const float4*)&Bs[k][col];
            *(float4*)&b[4] = *(const float4*)&Bs[k][col+4];
            #pragma unroll
            for (int i = 0; i < 8; ++i)
                #pragma unroll
                for (int j = 0; j < 8; ++j)
                    acc[i][j] = fmaf(a[i], b[j], acc[i][j]);
        }
    }
    float* Pp = P + ((size_t)s << 20) + (size_t)(bm + row) * N + bn + col;
    #pragma unroll
    for (int i = 0; i < 8; ++i) {
        *(float4*)(Pp)     = make_float4(acc[i][0], acc[i][1], acc[i][2], acc[i][3]);
        *(float4*)(Pp + 4) = make_float4(acc[i][4], acc[i][5], acc[i][6], acc[i][7]);
        Pp += N;
    }
}

// partial sums -> bias + relu (deterministic order)
__global__ void reduce_bias_relu(const float* __restrict__ P, const float* __restrict__ bias,
                                 float* __restrict__ outp, int S)
{
    int t = blockIdx.x * 256 + threadIdx.x;
    if (t >= NPROP * HDIM) return;
    int m = t >> 10, n = t & 1023;
    float s = bias[n];
    for (int i = 0; i < S; ++i) s += P[((size_t)i << 20) + ((size_t)m << 10) + n];
    outp[(size_t)m * HDIM + n] = fmaxf(s, 0.f);
}

// ---------------- heads: h7(1000x1024) @ w_cls(1024x21)+b, @ w_reg(1024x84)+b ----------------
__global__ void heads_kernel(const float* __restrict__ h7,
                             const float* __restrict__ wc, const float* __restrict__ bc,
                             const float* __restrict__ wr, const float* __restrict__ br,
                             float* __restrict__ cls, float* __restrict__ reg)
{
    __shared__ float hs[HDIM];
    int n = blockIdx.x;
    for (int t = threadIdx.x; t < HDIM; t += 128) hs[t] = h7[(size_t)n * HDIM + t];
    __syncthreads();
    int t = threadIdx.x;
    if (t < 21) {
        float s = 0.f;
        #pragma unroll 8
        for (int k = 0; k < HDIM; ++k) s = fmaf(hs[k], wc[k*21 + t], s);
        cls[n*21 + t] = s + bc[t];
    } else if (t < 105) {
        int c = t - 21;
        float s = 0.f;
        #pragma unroll 8
        for (int k = 0; k < HDIM; ++k) s = fmaf(hs[k], wr[k*84 + c], s);
        reg[n*84 + c] = s + br[c];
    }
}

__global__ void init_keys(u64* keys)
{
    int t = blockIdx.x * 256 + threadIdx.x;
    if (t < NPAD) keys[t] = ~0ull;
}

// ---------------- softmax + box decode + key build (per proposal) ----------------
__global__ void decode_kernel(const float* __restrict__ cls, const float* __restrict__ reg,
                              const float* __restrict__ props,
                              float* __restrict__ boxes_all, float* __restrict__ scores_all,
                              u64* __restrict__ keys)
{
    int n = blockIdx.x * 256 + threadIdx.x;
    if (n >= NPROP) return;
    float lg[21];
    float m = -3.4e38f;
    #pragma unroll
    for (int c = 0; c < 21; ++c) { lg[c] = cls[n*21 + c]; m = fmaxf(m, lg[c]); }
    float sum = 0.f;
    #pragma unroll
    for (int c = 0; c < 21; ++c) { lg[c] = expf(lg[c] - m); sum += lg[c]; }
    float p0 = props[n*4+0], p1 = props[n*4+1], p2 = props[n*4+2], p3 = props[n*4+3];
    float w = p2 - p0, h = p3 - p1;
    float cx = __fadd_rn(p0, __fmul_rn(0.5f, w));
    float cy = __fadd_rn(p1, __fmul_rn(0.5f, h));
    for (int c = 1; c < 21; ++c) {
        const float* r = reg + n*84 + c*4;
        float dx = r[0], dy = r[1];
        float dw = fminf(r[2], LOGC);
        float dh = fminf(r[3], LOGC);
        float pcx = __fadd_rn(__fmul_rn(dx, w), cx);
        float pcy = __fadd_rn(__fmul_rn(dy, h), cy);
        float pw = __fmul_rn(expf(dw), w);
        float ph = __fmul_rn(expf(dh), h);
        float x1 = __fsub_rn(pcx, __fmul_rn(0.5f, pw));
        float y1 = __fsub_rn(pcy, __fmul_rn(0.5f, ph));
        float x2 = __fadd_rn(pcx, __fmul_rn(0.5f, pw));
        float y2 = __fadd_rn(pcy, __fmul_rn(0.5f, ph));
        x1 = fminf(fmaxf(x1, 0.f), 800.f); y1 = fminf(fmaxf(y1, 0.f), 800.f);
        x2 = fminf(fmaxf(x2, 0.f), 800.f); y2 = fminf(fmaxf(y2, 0.f), 800.f);
        int i = n*20 + (c - 1);
        float sc = lg[c] / sum;
        boxes_all[i*4+0] = x1; boxes_all[i*4+1] = y1;
        boxes_all[i*4+2] = x2; boxes_all[i*4+3] = y2;
        scores_all[i] = sc;
        keys[i] = mkkey(sc, (unsigned)i);
    }
}

// ---------------- bitonic sort of one 2048 run (ascending keys) ----------------
__global__ void sort_runs(u64* keys)
{
    __shared__ u64 sk[2048];
    int tid = threadIdx.x;
    u64* base = keys + (size_t)blockIdx.x * 2048;
    for (int t = tid; t < 2048; t += 256) sk[t] = base[t];
    for (int k = 2; k <= 2048; k <<= 1)
        for (int j = k >> 1; j > 0; j >>= 1) {
            __syncthreads();
            for (int idx = tid; idx < 2048; idx += 256) {
                int ixj = idx ^ j;
                if (ixj > idx) {
                    u64 a = sk[idx], b = sk[ixj];
                    bool up = (idx & k) == 0;
                    if ((a > b) == up) { sk[idx] = b; sk[ixj] = a; }
                }
            }
        }
    __syncthreads();
    for (int t = tid; t < 2048; t += 256) base[t] = sk[t];
}

// merge pairs of ascending 2048-runs, keep lowest 2048 (= top scores), sorted
__global__ void merge_runs(const u64* __restrict__ in, u64* __restrict__ out, int nin)
{
    __shared__ u64 sk[2048];
    int b = blockIdx.x, tid = threadIdx.x;
    const u64* A = in + ((size_t)(2*b)) * 2048;
    u64* O = out + (size_t)b * 2048;
    if (2*b + 1 < nin) {
        const u64* B = in + ((size_t)(2*b + 1)) * 2048;
        for (int t = tid; t < 2048; t += 256) {
            u64 a = A[t], bb = B[2047 - t];
            sk[t] = a < bb ? a : bb;          // bitonic split: set of 2048 smallest, bitonic
        }
        for (int j = 1024; j > 0; j >>= 1) {
            __syncthreads();
            for (int idx = tid; idx < 2048; idx += 256) {
                int ixj = idx ^ j;
                if (ixj > idx) {
                    u64 x = sk[idx], y = sk[ixj];
                    if (x > y) { sk[idx] = y; sk[ixj] = x; }
                }
            }
        }
        __syncthreads();
        for (int t = tid; t < 2048; t += 256) O[t] = sk[t];
    } else {
        for (int t = tid; t < 2048; t += 256) O[t] = A[t];
    }
}

// gather top-2000: scores, boxes, labels, offset boxes
__global__ void nms_prep(const u64* __restrict__ keys, const float* __restrict__ scores_all,
                         const float* __restrict__ boxes_all, float* __restrict__ tops,
                         float* __restrict__ bx, int* __restrict__ lab, float* __restrict__ obx)
{
    int i = blockIdx.x * 256 + threadIdx.x;
    if (i >= KPRE) return;
    u64 k = keys[i];
    unsigned idx = (unsigned)(k & 0xffffffffull);
    tops[i] = scores_all[idx];
    float4 b = *(const float4*)(boxes_all + (size_t)idx * 4);
    *(float4*)(bx + (size_t)i * 4) = b;
    int l = (int)(idx % 20u) + 1;
    lab[i] = l;
    float off = (float)l * 10000.f;
    float4 ob = make_float4(b.x + off, b.y + off, b.z + off, b.w + off);
    *(float4*)(obx + (size_t)i * 4) = ob;
}

// suppression bitmask: row i, 32 words of 64 j's. bit set = (j>i) && !(iou<=0.3) (NaN suppresses, as ref)
__global__ void iou_mask(const float* __restrict__ obx, u64* __restrict__ mask)
{
    int i = blockIdx.x;
    int lane = threadIdx.x;
    const float4 bi = *(const float4*)(obx + (size_t)i * 4);
    float a1 = __fmul_rn(bi.z - bi.x, bi.w - bi.y);
    for (int w = 0; w < 32; ++w) {
        int j = (w << 6) + lane;
        bool supp = false;
        if (j > i && j < KPRE) {
            float4 bj = *(const float4*)(obx + (size_t)j * 4);
            float a2 = __fmul_rn(bj.z - bj.x, bj.w - bj.y);
            float xl = fmaxf(bi.x, bj.x), yt = fmaxf(bi.y, bj.y);
            float xr = fminf(bi.z, bj.z), yb = fminf(bi.w, bj.w);
            float inter = __fmul_rn(fmaxf(xr - xl, 0.f), fmaxf(yb - yt, 0.f));
            float uni = __fsub_rn(__fadd_rn(a1, a2), inter);
            float iou = inter / uni;            // 0/0 -> NaN -> suppress (matches ref)
            supp = !(iou <= 0.3f);
        }
        u64 word = __ballot((int)supp);
        if (lane == 0) mask[(size_t)i * 32 + w] = word;
    }
}

// single-wave sequential NMS scan; lanes 0..31 own the 32 removed-words; 8-deep row prefetch
__global__ void nms_scan_kernel(const u64* __restrict__ mask, const float* __restrict__ tops,
                                float* __restrict__ fsc, u64* __restrict__ keys2)
{
    int lane = threadIdx.x;
    u64 removed = 0;
    if (lane < 32) {
        int base = lane * 64;
        for (int b = 0; b < 64; ++b) {
            int i = base + b;
            float s = (i < KPRE) ? tops[i] : -1.0f;
            if (!(s > 0.05f)) removed |= (1ull << b);   // invalid == pre-removed
        }
    }
    bool ld = lane < 32;
#define LR(i) ((ld && (i) < KPRE) ? mask[(size_t)(i) * 32 + lane] : 0ull)
    u64 p0=LR(0),p1=LR(1),p2=LR(2),p3=LR(3),p4=LR(4),p5=LR(5),p6=LR(6),p7=LR(7);
    for (int i = 0; i < KPRE; i += 8) {
        u64 n0=LR(i+8),n1=LR(i+9),n2=LR(i+10),n3=LR(i+11),n4=LR(i+12),n5=LR(i+13),n6=LR(i+14),n7=LR(i+15);
#define PROC(ii, pr) { u64 rw = __shfl(removed, (ii) >> 6); if (!((rw >> ((ii) & 63)) & 1ull)) removed |= pr; }
        PROC(i+0, p0) PROC(i+1, p1) PROC(i+2, p2) PROC(i+3, p3)
        PROC(i+4, p4) PROC(i+5, p5) PROC(i+6, p6) PROC(i+7, p7)
        p0=n0;p1=n1;p2=n2;p3=n3;p4=n4;p5=n5;p6=n6;p7=n7;
    }
#undef PROC
#undef LR
    for (int kk = 0; kk < 32; ++kk) {
        int t = (kk << 6) + lane;
        u64 rw = __shfl(removed, kk);
        if (t < KPRE) {
            float s = ((rw >> lane) & 1ull) ? -1.0f : tops[t];
            fsc[t] = s;
            keys2[t] = mkkey(s, (unsigned)t);
        } else {
            keys2[t] = ~0ull;
        }
    }
}

// sort 2048 final keys, emit top-100 (boxes, scores, labels)
__global__ void final_sort_out(const u64* __restrict__ keys2, const float* __restrict__ fsc,
                               const float* __restrict__ bx, const int* __restrict__ lab,
                               float* __restrict__ outp)
{
    __shared__ u64 sk[2048];
    int tid = threadIdx.x;
    for (int t = tid; t < 2048; t += 256) sk[t] = keys2[t];
    for (int k = 2; k <= 2048; k <<= 1)
        for (int j = k >> 1; j > 0; j >>= 1) {
            __syncthreads();
            for (int idx = tid; idx < 2048; idx += 256) {
                int ixj = idx ^ j;
                if (ixj > idx) {
                    u64 a = sk[idx], b = sk[ixj];
                    bool up = (idx & k) == 0;
                    if ((a > b) == up) { sk[idx] = b; sk[ixj] = a; }
                }
            }
        }
    __syncthreads();
    if (tid < 100) {
        u64 key = sk[tid];
        unsigned i2 = (unsigned)(key & 0xffffffffull);
        float4 b4 = *(const float4*)(bx + (size_t)i2 * 4);
        outp[tid*4+0] = b4.x; outp[tid*4+1] = b4.y; outp[tid*4+2] = b4.z; outp[tid*4+3] = b4.w;
        outp[400 + tid] = fsc[i2];
        outp[500 + tid] = (float)lab[i2];
    }
}

extern "C" void kernel_launch(void* const* d_in, const int* in_sizes, int n_in,
                              void* d_out, int out_size, void* d_ws, size_t ws_size,
                              hipStream_t stream)
{
    const float* feat  = (const float*)d_in[0];
    const float* props = (const float*)d_in[1];
    const float* w6    = (const float*)d_in[2];
    const float* b6    = (const float*)d_in[3];
    const float* w7    = (const float*)d_in[4];
    const float* b7    = (const float*)d_in[5];
    const float* wcls  = (const float*)d_in[6];
    const float* bcls  = (const float*)d_in[7];
    const float* wreg  = (const float*)d_in[8];
    const float* breg  = (const float*)d_in[9];
    float* outp = (float*)d_out;

    char* w = (char*)d_ws;
    size_t off = 0;
    auto take = [&](size_t bytes) -> char* {
        char* p = w + off;
        off = (off + bytes + 255) & ~(size_t)255;
        return p;
    };
    float* pooled = (float*)take((size_t)NPROP * KDIM * 4);          // 100.35 MB
    // split-K factor chosen by available workspace (constant per process -> deterministic)
    int S6 = (ws_size >= off + 16ull * (1u << 22) + (14ull << 20)) ? 16 : 4;
    float* partial = (float*)take((size_t)S6 * (1u << 22));          // S6 * 4 MB
    float* h6  = (float*)take(4ull << 20);
    float* h7  = (float*)take(4ull << 20);
    float* cls = (float*)take((size_t)NPROP * 21 * 4);
    float* reg = (float*)take((size_t)NPROP * 84 * 4);
    float* boxes_all  = (float*)take((size_t)NBOX * 16);
    float* scores_all = (float*)take((size_t)NBOX * 4);
    u64* keysA = (u64*)take((size_t)NPAD * 8);
    u64* keysB = (u64*)take((size_t)NPAD * 8);
    float* tops = (float*)take((size_t)KPRE * 4);
    float* bx   = (float*)take((size_t)KPRE * 16);
    int*   lab  = (int*)take((size_t)KPRE * 4);
    float* obx  = (float*)take((size_t)KPRE * 16);
    u64* mask   = (u64*)take((size_t)KPRE * 32 * 8);
    float* fsc  = (float*)take((size_t)KPRE * 4);
    u64* keys2  = (u64*)take(2048 * 8);

    roi_pool_kernel<<<NPROP, 256, 0, stream>>>(feat, props, pooled);

    gemm_splitk<<<dim3(8, 8, S6), 256, 0, stream>>>(pooled, w6, partial, NPROP, KDIM, KDIM / S6);
    reduce_bias_relu<<<4000, 256, 0, stream>>>(partial, b6, h6, S6);

    gemm_splitk<<<dim3(8, 8, 4), 256, 0, stream>>>(h6, w7, partial, NPROP, HDIM, 256);
    reduce_bias_relu<<<4000, 256, 0, stream>>>(partial, b7, h7, 4);

    heads_kernel<<<NPROP, 128, 0, stream>>>(h7, wcls, bcls, wreg, breg, cls, reg);

    init_keys<<<80, 256, 0, stream>>>(keysA);
    decode_kernel<<<4, 256, 0, stream>>>(cls, reg, props, boxes_all, scores_all, keysA);

    sort_runs<<<10, 256, 0, stream>>>(keysA);
    merge_runs<<<5, 256, 0, stream>>>(keysA, keysB, 10);
    merge_runs<<<3, 256, 0, stream>>>(keysB, keysA, 5);
    merge_runs<<<2, 256, 0, stream>>>(keysA, keysB, 3);
    merge_runs<<<1, 256, 0, stream>>>(keysB, keysA, 2);

    nms_prep<<<8, 256, 0, stream>>>(keysA, scores_all, boxes_all, tops, bx, lab, obx);
    iou_mask<<<KPRE, 64, 0, stream>>>(obx, mask);
    nms_scan_kernel<<<1, 64, 0, stream>>>(mask, tops, fsc, keys2);
    final_sort_out<<<1, 256, 0, stream>>>(keys2, fsc, bx, lab, outp);
}